// Round 6
// baseline (504.459 us; speedup 1.0000x reference)
//
#include <hip/hip_runtime.h>

#define NN 100000
#define NE 3200000
#define FIN 128
#define HD 16

#define BSH 8                        // bucket shift
#define BSPAN 256                    // nodes per bucket
#define NBKT 391                     // ceil(NN / BSPAN) == edge chunks
#define CAP 9216                     // bucket capacity: mean 8184 + ~11 sigma
#define TPB 512

#define FXS 1048576.0f               // 2^20 fixed-point scale
#define FXI (1.0f / 1048576.0f)

__device__ __forceinline__ float lo2f(unsigned u) {
    union { float f; unsigned i; } v; v.i = u << 16; return v.f;
}
__device__ __forceinline__ float hi2f(unsigned u) {
    union { float f; unsigned i; } v; v.i = u & 0xFFFF0000u; return v.f;
}
__device__ __forceinline__ ushort f2b(float f) {
    union { float f; unsigned u; } v; v.f = f;
    unsigned r = (v.u + 0x7FFFu + ((v.u >> 16) & 1u)) >> 16;   // RNE
    return (ushort)r;
}
__device__ __forceinline__ unsigned pck(float a, float b) {
    return (unsigned)f2b(a) | ((unsigned)f2b(b) << 16);
}

// LDS union across phases (max ~39.5 KB) + persistent dvs outside
union SMem {
    struct { int h[NBKT]; int sbuf[TPB]; int lcur[NBKT]; int gbase[NBKT];
             unsigned ebuf[8192]; } s;                       // phase 1: 39.5 KB
    struct { float wsm[FIN][HD]; int cnt[BSPAN]; } g;        // phase 2: 9.2 KB
    struct { int acc[BSPAN][HD + 1]; float w2s[HD * 2]; float b1s[HD]; } a1; // 17.6 KB
    struct { int acc2[BSPAN * 3]; } a2;                      // phase 4: 3 KB
};

// grid barrier: counter + broadcast flag (what grid.sync() is made of).
// All 391 blocks are co-resident by construction (see launch_bounds math).
__device__ __forceinline__ void gbar(int* bar, int phase) {
    __syncthreads();                 // drains each wave's vmcnt before arrival
    if (threadIdx.x == 0) {
        __threadfence();             // release: writeback this XCD's L2
        __hip_atomic_fetch_add(&bar[0], 1, __ATOMIC_RELEASE, __HIP_MEMORY_SCOPE_AGENT);
        if (blockIdx.x == 0) {
            while (__hip_atomic_load(&bar[0], __ATOMIC_ACQUIRE, __HIP_MEMORY_SCOPE_AGENT)
                   < phase * NBKT)
                __builtin_amdgcn_s_sleep(4);
            __hip_atomic_store(&bar[1], phase, __ATOMIC_RELEASE, __HIP_MEMORY_SCOPE_AGENT);
        } else {
            while (__hip_atomic_load(&bar[1], __ATOMIC_ACQUIRE, __HIP_MEMORY_SCOPE_AGENT)
                   < phase)
                __builtin_amdgcn_s_sleep(4);
        }
        __threadfence();             // acquire: invalidate L1 + XCD L2
    }
    __syncthreads();
}

// scatter one h1b row (16 bf16 feats) into int fixed-point accumulators
__device__ __forceinline__ void scat16(int* a, uint4 u0, uint4 u1) {
    atomicAdd(a + 0,  __float2int_rn(lo2f(u0.x) * FXS));
    atomicAdd(a + 1,  __float2int_rn(hi2f(u0.x) * FXS));
    atomicAdd(a + 2,  __float2int_rn(lo2f(u0.y) * FXS));
    atomicAdd(a + 3,  __float2int_rn(hi2f(u0.y) * FXS));
    atomicAdd(a + 4,  __float2int_rn(lo2f(u0.z) * FXS));
    atomicAdd(a + 5,  __float2int_rn(hi2f(u0.z) * FXS));
    atomicAdd(a + 6,  __float2int_rn(lo2f(u0.w) * FXS));
    atomicAdd(a + 7,  __float2int_rn(hi2f(u0.w) * FXS));
    atomicAdd(a + 8,  __float2int_rn(lo2f(u1.x) * FXS));
    atomicAdd(a + 9,  __float2int_rn(hi2f(u1.x) * FXS));
    atomicAdd(a + 10, __float2int_rn(lo2f(u1.y) * FXS));
    atomicAdd(a + 11, __float2int_rn(hi2f(u1.y) * FXS));
    atomicAdd(a + 12, __float2int_rn(lo2f(u1.z) * FXS));
    atomicAdd(a + 13, __float2int_rn(hi2f(u1.z) * FXS));
    atomicAdd(a + 14, __float2int_rn(lo2f(u1.w) * FXS));
    atomicAdd(a + 15, __float2int_rn(hi2f(u1.w) * FXS));
}

// 512 thr, min 4 waves/EU -> VGPR<=128 -> >=2 blocks/CU -> 512 co-resident >= 391
__global__ __launch_bounds__(TPB, 4) void k_all(
    const int* __restrict__ src, const int* __restrict__ dst,
    const float* __restrict__ x, const float* __restrict__ W1,
    const float* __restrict__ b1, const float* __restrict__ W2,
    const float* __restrict__ b2,
    int* __restrict__ gcnt, int* __restrict__ bar,
    unsigned* __restrict__ csrb, ushort* __restrict__ h1b,
    float* __restrict__ g_s, float* __restrict__ out)
{
    __shared__ SMem sm;
    __shared__ float dvs[BSPAN];     // persistent across phases 2-4
    int b = blockIdx.x, t = threadIdx.x;

    // ======== phase 1: partition with block-local counting sort ========
    for (int i = t; i < NBKT; i += TPB) sm.s.h[i] = 0;
    __syncthreads();
    int cq = b * 2048;               // int4 base (8192 edges / block)
    const int4* s4p = (const int4*)src;
    const int4* d4p = (const int4*)dst;
    int4 sv[4], dv[4];
    #pragma unroll
    for (int j = 0; j < 4; ++j) {
        int e4 = cq + j * TPB + t;
        if (e4 < NE / 4) {
            sv[j] = s4p[e4]; dv[j] = d4p[e4];
            atomicAdd(&sm.s.h[dv[j].x >> BSH], 1);
            atomicAdd(&sm.s.h[dv[j].y >> BSH], 1);
            atomicAdd(&sm.s.h[dv[j].z >> BSH], 1);
            atomicAdd(&sm.s.h[dv[j].w >> BSH], 1);
        }
    }
    __syncthreads();
    // inclusive scan of h -> sbuf
    sm.s.sbuf[t] = (t < NBKT) ? sm.s.h[t] : 0;
    __syncthreads();
    for (int off = 1; off < TPB; off <<= 1) {
        int v = 0;
        if (t >= off) v = sm.s.sbuf[t - off];
        __syncthreads();
        if (t >= off) sm.s.sbuf[t] += v;
        __syncthreads();
    }
    // reserve global runs; gbase[i] folds (i*CAP + reserve - excl)
    if (t < NBKT) {
        int c = sm.s.h[t];
        int excl = sm.s.sbuf[t] - c;
        sm.s.lcur[t] = excl;
        int gb = t * CAP - excl;
        if (c) gb += atomicAdd(&gcnt[t], c);
        sm.s.gbase[t] = gb;
    }
    __syncthreads();
    // insert into bucket-sorted LDS buffer
    #pragma unroll
    for (int j = 0; j < 4; ++j) {
        int e4 = cq + j * TPB + t;
        if (e4 < NE / 4) {
            int bk, p;
            bk = dv[j].x >> BSH; p = atomicAdd(&sm.s.lcur[bk], 1);
            sm.s.ebuf[p] = (unsigned)sv[j].x | ((unsigned)(dv[j].x & (BSPAN - 1)) << 17);
            bk = dv[j].y >> BSH; p = atomicAdd(&sm.s.lcur[bk], 1);
            sm.s.ebuf[p] = (unsigned)sv[j].y | ((unsigned)(dv[j].y & (BSPAN - 1)) << 17);
            bk = dv[j].z >> BSH; p = atomicAdd(&sm.s.lcur[bk], 1);
            sm.s.ebuf[p] = (unsigned)sv[j].z | ((unsigned)(dv[j].z & (BSPAN - 1)) << 17);
            bk = dv[j].w >> BSH; p = atomicAdd(&sm.s.lcur[bk], 1);
            sm.s.ebuf[p] = (unsigned)sv[j].w | ((unsigned)(dv[j].w & (BSPAN - 1)) << 17);
        }
    }
    __syncthreads();
    // stream out: consecutive pos -> consecutive gaddr within each bucket run
    int ecnt = NE - b * 8192; if (ecnt > 8192) ecnt = 8192;
    for (int p = t; p < ecnt; p += TPB) {
        unsigned pl = sm.s.ebuf[p];
        int lo = 0, hi = NBKT;
        while (lo < hi) { int mid = (lo + hi) >> 1;
                          if (sm.s.sbuf[mid] > p) hi = mid; else lo = mid + 1; }
        csrb[sm.s.gbase[lo] + p] = pl;
    }
    gbar(bar, 1);

    // ======== phase 2: per-bucket degree (LDS) + GEMM1 + bf16 pack ========
    int e0 = b * CAP, e1 = e0 + gcnt[b];
    for (int i = t; i < FIN * HD; i += TPB) sm.g.wsm[i >> 4][i & 15] = W1[i];
    if (t < BSPAN) sm.g.cnt[t] = 0;
    __syncthreads();
    for (int e = e0 + t; e < e1; e += TPB) atomicAdd(&sm.g.cnt[csrb[e] >> 17], 1);
    __syncthreads();
    if (t < BSPAN) dvs[t] = rsqrtf((float)sm.g.cnt[t] + 1.0f);
    __syncthreads();
    {
        int loc = t >> 1, half = t & 1;
        int node = b * BSPAN + loc;
        if (node < NN) {
            int g8 = half * 8;
            const float4* xr = (const float4*)(x + (size_t)node * FIN);
            float a0 = 0.f, a1 = 0.f, a2 = 0.f, a3 = 0.f;
            float a4 = 0.f, a5 = 0.f, a6 = 0.f, a7 = 0.f;
            #pragma unroll
            for (int k4 = 0; k4 < FIN / 4; ++k4) {
                float4 v = xr[k4];
                #pragma unroll
                for (int kk = 0; kk < 4; ++kk) {
                    float vk = (kk == 0) ? v.x : (kk == 1) ? v.y : (kk == 2) ? v.z : v.w;
                    float4 w0 = *(const float4*)&sm.g.wsm[k4 * 4 + kk][g8];
                    float4 w1 = *(const float4*)&sm.g.wsm[k4 * 4 + kk][g8 + 4];
                    a0 += vk * w0.x; a1 += vk * w0.y; a2 += vk * w0.z; a3 += vk * w0.w;
                    a4 += vk * w1.x; a5 += vk * w1.y; a6 += vk * w1.z; a7 += vk * w1.w;
                }
            }
            float di = dvs[loc];
            uint4 r = {pck(a0 * di, a1 * di), pck(a2 * di, a3 * di),
                       pck(a4 * di, a5 * di), pck(a6 * di, a7 * di)};
            *(uint4*)(h1b + (size_t)node * HD + g8) = r;
        }
    }
    gbar(bar, 2);

    // ======== phase 3: LDS int scatter-agg + ReLU + fused (h2 @ W2) ========
    for (int i = t; i < BSPAN * (HD + 1); i += TPB) ((int*)sm.a1.acc)[i] = 0;
    if (t < HD * 2) sm.a1.w2s[t] = W2[t];
    else if (t < HD * 3) sm.a1.b1s[t - HD * 2] = b1[t - HD * 2];
    __syncthreads();
    {
        int e = e0 + t;
        for (; e + TPB < e1; e += 2 * TPB) {     // 2 independent gather chains
            unsigned pa = csrb[e];
            unsigned pb = csrb[e + TPB];
            const uint4* ra = (const uint4*)(h1b + (size_t)(pa & 0x1FFFF) * HD);
            const uint4* rb = (const uint4*)(h1b + (size_t)(pb & 0x1FFFF) * HD);
            uint4 a0 = ra[0], a1 = ra[1];
            uint4 c0 = rb[0], c1 = rb[1];
            scat16(sm.a1.acc[pa >> 17], a0, a1);
            scat16(sm.a1.acc[pb >> 17], c0, c1);
        }
        if (e < e1) {
            unsigned p = csrb[e];
            const uint4* r = (const uint4*)(h1b + (size_t)(p & 0x1FFFF) * HD);
            uint4 u0 = r[0], u1 = r[1];
            scat16(sm.a1.acc[p >> 17], u0, u1);
        }
    }
    __syncthreads();
    {
        int loc = t >> 1, half = t & 1;
        int node = b * BSPAN + loc;
        if (node < NN) {
            float di = dvs[loc];
            const uint4 svv = *(const uint4*)(h1b + (size_t)node * HD + half * 8);
            float sf[8] = {lo2f(svv.x), hi2f(svv.x), lo2f(svv.y), hi2f(svv.y),
                           lo2f(svv.z), hi2f(svv.z), lo2f(svv.w), hi2f(svv.w)};
            const int* a = sm.a1.acc[loc] + half * 8;
            const float* bb = sm.a1.b1s + half * 8;
            const float* ww = sm.a1.w2s + half * 16;
            float p0 = 0.f, p1 = 0.f;
            #pragma unroll
            for (int k = 0; k < 8; ++k) {
                float v = fmaxf(di * ((float)a[k] * FXI + sf[k]) + bb[k], 0.f);
                p0 += v * ww[k * 2];
                p1 += v * ww[k * 2 + 1];
            }
            p0 += __shfl_xor(p0, 1, 64);
            p1 += __shfl_xor(p1, 1, 64);
            if (half == 0) {
                float2 r = {p0 * di, p1 * di};
                *(float2*)(g_s + (size_t)node * 2) = r;
            }
        }
    }
    gbar(bar, 3);

    // ======== phase 4: LDS int scatter-agg + bias + log_softmax ========
    for (int i = t; i < BSPAN * 3; i += TPB) sm.a2.acc2[i] = 0;
    __syncthreads();
    {
        int e = e0 + t;
        for (; e + TPB < e1; e += 2 * TPB) {
            unsigned pa = csrb[e];
            unsigned pb = csrb[e + TPB];
            float2 va = *(const float2*)(g_s + (size_t)(pa & 0x1FFFF) * 2);
            float2 vb = *(const float2*)(g_s + (size_t)(pb & 0x1FFFF) * 2);
            int la = (pa >> 17) * 3, lb = (pb >> 17) * 3;
            atomicAdd(&sm.a2.acc2[la],     __float2int_rn(va.x * FXS));
            atomicAdd(&sm.a2.acc2[la + 1], __float2int_rn(va.y * FXS));
            atomicAdd(&sm.a2.acc2[lb],     __float2int_rn(vb.x * FXS));
            atomicAdd(&sm.a2.acc2[lb + 1], __float2int_rn(vb.y * FXS));
        }
        if (e < e1) {
            unsigned p = csrb[e];
            float2 v = *(const float2*)(g_s + (size_t)(p & 0x1FFFF) * 2);
            int l = (p >> 17) * 3;
            atomicAdd(&sm.a2.acc2[l],     __float2int_rn(v.x * FXS));
            atomicAdd(&sm.a2.acc2[l + 1], __float2int_rn(v.y * FXS));
        }
    }
    __syncthreads();
    if (t < BSPAN) {
        int node = b * BSPAN + t;
        if (node < NN) {
            float di = dvs[t];
            float2 svv = *(const float2*)(g_s + (size_t)node * 2);
            float o0 = di * ((float)sm.a2.acc2[t * 3] * FXI + svv.x) + b2[0];
            float o1 = di * ((float)sm.a2.acc2[t * 3 + 1] * FXI + svv.y) + b2[1];
            float mx = fmaxf(o0, o1);
            float l = mx + logf(__expf(o0 - mx) + __expf(o1 - mx));
            float2 r = {o0 - l, o1 - l};
            *(float2*)(out + (size_t)node * 2) = r;
        }
    }
}

extern "C" void kernel_launch(void* const* d_in, const int* in_sizes, int n_in,
                              void* d_out, int out_size, void* d_ws, size_t ws_size,
                              hipStream_t stream) {
    const float* x   = (const float*)d_in[0];
    const int* ei    = (const int*)d_in[1];
    const int* src   = ei;
    const int* dst   = ei + NE;
    const float* W1  = (const float*)d_in[2];
    const float* b1  = (const float*)d_in[3];
    const float* W2  = (const float*)d_in[4];
    const float* b2  = (const float*)d_in[5];
    float* out = (float*)d_out;

    char* w = (char*)d_ws;
    int*   gcnt        = (int*)w;            w += NBKT * 4;                 // 1.6 KB
    int*   bar         = (int*)w;            w += 2 * 4;                    // arrive, flag
    unsigned int* csrb = (unsigned int*)w;   w += (size_t)NBKT * CAP * 4;   // 14.4 MB
    ushort* h1b        = (ushort*)w;         w += (size_t)NN * HD * 2;      // 3.2 MB
    float* g_s         = (float*)w;          w += NN * 2 * 4;               // 800 KB

    hipMemsetAsync(gcnt, 0, (NBKT + 2) * 4, stream);   // gcnt + barrier state
    k_all<<<NBKT, TPB, 0, stream>>>(src, dst, x, W1, b1, W2, b2,
                                    gcnt, bar, csrb, h1b, g_s, out);
}

// Round 7
// 200.149 us; speedup vs baseline: 2.5204x; 2.5204x over previous
//
#include <hip/hip_runtime.h>

#define NN 100000
#define NE 3200000
#define FIN 128
#define HD 16

#define BSH 8                        // bucket shift
#define BSPAN 256                    // nodes per bucket
#define NBKT 391                     // ceil(NN / BSPAN) == edge chunks
#define CAP 9216                     // bucket capacity: mean 8184 + ~11 sigma
#define TPB 512

#define FXS 1048576.0f               // 2^20 fixed-point scale
#define FXI (1.0f / 1048576.0f)

__device__ __forceinline__ float lo2f(unsigned u) {
    union { float f; unsigned i; } v; v.i = u << 16; return v.f;
}
__device__ __forceinline__ float hi2f(unsigned u) {
    union { float f; unsigned i; } v; v.i = u & 0xFFFF0000u; return v.f;
}
__device__ __forceinline__ ushort f2b(float f) {
    union { float f; unsigned u; } v; v.f = f;
    unsigned r = (v.u + 0x7FFFu + ((v.u >> 16) & 1u)) >> 16;   // RNE
    return (ushort)r;
}
__device__ __forceinline__ unsigned pck(float a, float b) {
    return (unsigned)f2b(a) | ((unsigned)f2b(b) << 16);
}

// ---- partition with block-local counting sort -> coalesced csrb writes ----
// R4 lesson: scattered 4B stores = 9x write amplification (118 MB, ~30 us).
// R6 proof: LDS-sorted stream-out cuts WRITE_SIZE to ~22 MB.
__global__ __launch_bounds__(TPB) void k_scat(const int* __restrict__ src,
                                              const int* __restrict__ dst,
                                              int* __restrict__ gcnt,
                                              unsigned* __restrict__ csrb) {
    __shared__ int h[NBKT];
    __shared__ int sbuf[TPB];
    __shared__ int lcur[NBKT];
    __shared__ int gbase[NBKT];
    __shared__ unsigned ebuf[8192];
    int b = blockIdx.x, t = threadIdx.x;
    for (int i = t; i < NBKT; i += TPB) h[i] = 0;
    __syncthreads();
    int cq = b * 2048;               // int4 base (8192 edges / block)
    const int4* s4p = (const int4*)src;
    const int4* d4p = (const int4*)dst;
    int4 sv[4], dv[4];
    #pragma unroll
    for (int j = 0; j < 4; ++j) {
        int e4 = cq + j * TPB + t;
        if (e4 < NE / 4) {
            sv[j] = s4p[e4]; dv[j] = d4p[e4];
            atomicAdd(&h[dv[j].x >> BSH], 1);
            atomicAdd(&h[dv[j].y >> BSH], 1);
            atomicAdd(&h[dv[j].z >> BSH], 1);
            atomicAdd(&h[dv[j].w >> BSH], 1);
        }
    }
    __syncthreads();
    // inclusive scan of h -> sbuf
    sbuf[t] = (t < NBKT) ? h[t] : 0;
    __syncthreads();
    for (int off = 1; off < TPB; off <<= 1) {
        int v = 0;
        if (t >= off) v = sbuf[t - off];
        __syncthreads();
        if (t >= off) sbuf[t] += v;
        __syncthreads();
    }
    // reserve global runs; gbase[i] folds (i*CAP + reserve - excl)
    if (t < NBKT) {
        int c = h[t];
        int excl = sbuf[t] - c;
        lcur[t] = excl;
        int gb = t * CAP - excl;
        if (c) gb += atomicAdd(&gcnt[t], c);
        gbase[t] = gb;
    }
    __syncthreads();
    // insert into bucket-sorted LDS buffer
    #pragma unroll
    for (int j = 0; j < 4; ++j) {
        int e4 = cq + j * TPB + t;
        if (e4 < NE / 4) {
            int bk, p;
            bk = dv[j].x >> BSH; p = atomicAdd(&lcur[bk], 1);
            ebuf[p] = (unsigned)sv[j].x | ((unsigned)(dv[j].x & (BSPAN - 1)) << 17);
            bk = dv[j].y >> BSH; p = atomicAdd(&lcur[bk], 1);
            ebuf[p] = (unsigned)sv[j].y | ((unsigned)(dv[j].y & (BSPAN - 1)) << 17);
            bk = dv[j].z >> BSH; p = atomicAdd(&lcur[bk], 1);
            ebuf[p] = (unsigned)sv[j].z | ((unsigned)(dv[j].z & (BSPAN - 1)) << 17);
            bk = dv[j].w >> BSH; p = atomicAdd(&lcur[bk], 1);
            ebuf[p] = (unsigned)sv[j].w | ((unsigned)(dv[j].w & (BSPAN - 1)) << 17);
        }
    }
    __syncthreads();
    // stream out: consecutive pos -> consecutive gaddr within each bucket run
    int ecnt = NE - b * 8192; if (ecnt > 8192) ecnt = 8192;
    for (int p = t; p < ecnt; p += TPB) {
        unsigned pl = ebuf[p];
        int lo = 0, hi = NBKT;
        while (lo < hi) { int mid = (lo + hi) >> 1;
                          if (sbuf[mid] > p) hi = mid; else lo = mid + 1; }
        csrb[gbase[lo] + p] = pl;
    }
}

// ---- bucket-block GEMM: LDS degree count from csrb + dinv + h1b ----
// block = 1 bucket (256 nodes), 512 threads: 2 threads/node, 8 outputs each.
__global__ __launch_bounds__(TPB) void k_gemm1d(const int* __restrict__ gcnt,
                                                const unsigned int* __restrict__ csrb,
                                                const float* __restrict__ x,
                                                const float* __restrict__ W1,
                                                float* __restrict__ dinv,
                                                ushort* __restrict__ h1b) {
    __shared__ float wsm[FIN][HD];   // 8 KB
    __shared__ int cnt[BSPAN];
    __shared__ float dvs[BSPAN];
    int b = blockIdx.x, t = threadIdx.x;
    if (t < BSPAN) cnt[t] = 0;
    for (int i = t; i < FIN * HD; i += TPB) wsm[i >> 4][i & 15] = W1[i];
    __syncthreads();
    int e0 = b * CAP, e1 = e0 + gcnt[b];
    for (int e = e0 + t; e < e1; e += TPB) atomicAdd(&cnt[csrb[e] >> 17], 1);
    __syncthreads();
    if (t < BSPAN) {
        int node = b * BSPAN + t;
        float di = rsqrtf((float)cnt[t] + 1.0f);
        dvs[t] = di;
        if (node < NN) dinv[node] = di;
    }
    __syncthreads();
    int loc = t >> 1, half = t & 1;
    int node = b * BSPAN + loc;
    if (node >= NN) return;
    int g = half * 8;
    const float4* xr = (const float4*)(x + (size_t)node * FIN);
    float a0 = 0.f, a1 = 0.f, a2 = 0.f, a3 = 0.f;
    float a4 = 0.f, a5 = 0.f, a6 = 0.f, a7 = 0.f;
    #pragma unroll
    for (int k4 = 0; k4 < FIN / 4; ++k4) {
        float4 v = xr[k4];
        #pragma unroll
        for (int kk = 0; kk < 4; ++kk) {
            float vk = (kk == 0) ? v.x : (kk == 1) ? v.y : (kk == 2) ? v.z : v.w;
            float4 w0 = *(const float4*)&wsm[k4 * 4 + kk][g];
            float4 w1 = *(const float4*)&wsm[k4 * 4 + kk][g + 4];
            a0 += vk * w0.x; a1 += vk * w0.y; a2 += vk * w0.z; a3 += vk * w0.w;
            a4 += vk * w1.x; a5 += vk * w1.y; a6 += vk * w1.z; a7 += vk * w1.w;
        }
    }
    float di = dvs[loc];
    uint4 r = {pck(a0 * di, a1 * di), pck(a2 * di, a3 * di),
               pck(a4 * di, a5 * di), pck(a6 * di, a7 * di)};
    *(uint4*)(h1b + (size_t)node * HD + g) = r;
}

// scatter one h1b row (16 bf16 feats) into int fixed-point accumulators
__device__ __forceinline__ void scat16(int* a, uint4 u0, uint4 u1) {
    atomicAdd(a + 0,  __float2int_rn(lo2f(u0.x) * FXS));
    atomicAdd(a + 1,  __float2int_rn(hi2f(u0.x) * FXS));
    atomicAdd(a + 2,  __float2int_rn(lo2f(u0.y) * FXS));
    atomicAdd(a + 3,  __float2int_rn(hi2f(u0.y) * FXS));
    atomicAdd(a + 4,  __float2int_rn(lo2f(u0.z) * FXS));
    atomicAdd(a + 5,  __float2int_rn(hi2f(u0.z) * FXS));
    atomicAdd(a + 6,  __float2int_rn(lo2f(u0.w) * FXS));
    atomicAdd(a + 7,  __float2int_rn(hi2f(u0.w) * FXS));
    atomicAdd(a + 8,  __float2int_rn(lo2f(u1.x) * FXS));
    atomicAdd(a + 9,  __float2int_rn(hi2f(u1.x) * FXS));
    atomicAdd(a + 10, __float2int_rn(lo2f(u1.y) * FXS));
    atomicAdd(a + 11, __float2int_rn(hi2f(u1.y) * FXS));
    atomicAdd(a + 12, __float2int_rn(lo2f(u1.z) * FXS));
    atomicAdd(a + 13, __float2int_rn(hi2f(u1.z) * FXS));
    atomicAdd(a + 14, __float2int_rn(lo2f(u1.w) * FXS));
    atomicAdd(a + 15, __float2int_rn(hi2f(u1.w) * FXS));
}

// ---- layer-1: per-bucket LDS int scatter-accumulate + ReLU + fused (h2@W2) ----
__global__ __launch_bounds__(TPB) void k_aggs1(const int* __restrict__ gcnt,
                                               const unsigned int* __restrict__ csrb,
                                               const ushort* __restrict__ h1b,
                                               const float* __restrict__ dinv,
                                               const float* __restrict__ b1,
                                               const float* __restrict__ W2,
                                               float* __restrict__ g_s) {
    __shared__ int acc[BSPAN][HD + 1];   // 17.4 KB, stride-17 spreads banks
    __shared__ float w2s[HD * 2];
    __shared__ float b1s[HD];
    int b = blockIdx.x, t = threadIdx.x;
    for (int i = t; i < BSPAN * (HD + 1); i += TPB) ((int*)acc)[i] = 0;
    if (t < HD * 2) w2s[t] = W2[t];
    else if (t < HD * 3) b1s[t - HD * 2] = b1[t - HD * 2];
    __syncthreads();
    int e0 = b * CAP, e1 = e0 + gcnt[b];
    int e = e0 + t;
    for (; e + TPB < e1; e += 2 * TPB) {     // 2 independent gather chains
        unsigned pa = csrb[e];
        unsigned pb = csrb[e + TPB];
        const uint4* ra = (const uint4*)(h1b + (size_t)(pa & 0x1FFFF) * HD);
        const uint4* rb = (const uint4*)(h1b + (size_t)(pb & 0x1FFFF) * HD);
        uint4 a0 = ra[0], a1 = ra[1];
        uint4 c0 = rb[0], c1 = rb[1];
        scat16(acc[pa >> 17], a0, a1);
        scat16(acc[pb >> 17], c0, c1);
    }
    if (e < e1) {
        unsigned p = csrb[e];
        const uint4* r = (const uint4*)(h1b + (size_t)(p & 0x1FFFF) * HD);
        uint4 u0 = r[0], u1 = r[1];
        scat16(acc[p >> 17], u0, u1);
    }
    __syncthreads();
    // epilogue: 2 threads per node (8 features each), pair-reduce via shfl
    int loc = t >> 1, half = t & 1;
    int node = b * BSPAN + loc;
    if (node < NN) {
        float di = dinv[node];
        const uint4 sv = *(const uint4*)(h1b + (size_t)node * HD + half * 8);
        float sf[8] = {lo2f(sv.x), hi2f(sv.x), lo2f(sv.y), hi2f(sv.y),
                       lo2f(sv.z), hi2f(sv.z), lo2f(sv.w), hi2f(sv.w)};
        const int* a = acc[loc] + half * 8;
        const float* bb = b1s + half * 8;
        const float* ww = w2s + half * 16;
        float p0 = 0.f, p1 = 0.f;
        #pragma unroll
        for (int k = 0; k < 8; ++k) {
            float v = fmaxf(di * ((float)a[k] * FXI + sf[k]) + bb[k], 0.f);
            p0 += v * ww[k * 2];
            p1 += v * ww[k * 2 + 1];
        }
        p0 += __shfl_xor(p0, 1, 64);
        p1 += __shfl_xor(p1, 1, 64);
        if (half == 0) {
            float2 r = {p0 * di, p1 * di};
            *(float2*)(g_s + (size_t)node * 2) = r;
        }
    }
}

// ---- layer-2: per-bucket LDS int scatter-accumulate + bias + log_softmax ----
__global__ __launch_bounds__(TPB) void k_aggs2(const int* __restrict__ gcnt,
                                               const unsigned int* __restrict__ csrb,
                                               const float* __restrict__ g_s,
                                               const float* __restrict__ dinv,
                                               const float* __restrict__ b2,
                                               float* __restrict__ out) {
    __shared__ int acc[BSPAN * 3];   // stride-3 spreads banks
    int b = blockIdx.x, t = threadIdx.x;
    for (int i = t; i < BSPAN * 3; i += TPB) acc[i] = 0;
    __syncthreads();
    int e0 = b * CAP, e1 = e0 + gcnt[b];
    int e = e0 + t;
    for (; e + TPB < e1; e += 2 * TPB) {
        unsigned pa = csrb[e];
        unsigned pb = csrb[e + TPB];
        float2 va = *(const float2*)(g_s + (size_t)(pa & 0x1FFFF) * 2);
        float2 vb = *(const float2*)(g_s + (size_t)(pb & 0x1FFFF) * 2);
        int la = (pa >> 17) * 3, lb = (pb >> 17) * 3;
        atomicAdd(&acc[la],     __float2int_rn(va.x * FXS));
        atomicAdd(&acc[la + 1], __float2int_rn(va.y * FXS));
        atomicAdd(&acc[lb],     __float2int_rn(vb.x * FXS));
        atomicAdd(&acc[lb + 1], __float2int_rn(vb.y * FXS));
    }
    if (e < e1) {
        unsigned p = csrb[e];
        float2 v = *(const float2*)(g_s + (size_t)(p & 0x1FFFF) * 2);
        int l = (p >> 17) * 3;
        atomicAdd(&acc[l],     __float2int_rn(v.x * FXS));
        atomicAdd(&acc[l + 1], __float2int_rn(v.y * FXS));
    }
    __syncthreads();
    if (t < BSPAN) {
        int node = b * BSPAN + t;
        if (node < NN) {
            float di = dinv[node];
            float2 sv = *(const float2*)(g_s + (size_t)node * 2);
            float o0 = di * ((float)acc[t * 3] * FXI + sv.x) + b2[0];
            float o1 = di * ((float)acc[t * 3 + 1] * FXI + sv.y) + b2[1];
            float mx = fmaxf(o0, o1);
            float l = mx + logf(__expf(o0 - mx) + __expf(o1 - mx));
            float2 r = {o0 - l, o1 - l};
            *(float2*)(out + (size_t)node * 2) = r;
        }
    }
}

extern "C" void kernel_launch(void* const* d_in, const int* in_sizes, int n_in,
                              void* d_out, int out_size, void* d_ws, size_t ws_size,
                              hipStream_t stream) {
    const float* x   = (const float*)d_in[0];
    const int* ei    = (const int*)d_in[1];
    const int* src   = ei;
    const int* dst   = ei + NE;
    const float* W1  = (const float*)d_in[2];
    const float* b1  = (const float*)d_in[3];
    const float* W2  = (const float*)d_in[4];
    const float* b2  = (const float*)d_in[5];
    float* out = (float*)d_out;

    char* w = (char*)d_ws;
    int*   gcnt        = (int*)w;            w += NBKT * 4;                 // 1.6 KB
    float* dinv        = (float*)w;          w += NN * 4;                   // 400 KB
    unsigned int* csrb = (unsigned int*)w;   w += (size_t)NBKT * CAP * 4;   // 14.4 MB
    ushort* h1b        = (ushort*)w;         w += (size_t)NN * HD * 2;      // 3.2 MB
    float* g_s         = (float*)w;          w += NN * 2 * 4;               // 800 KB

    hipMemsetAsync(gcnt, 0, NBKT * 4, stream);
    k_scat   <<<NBKT, TPB, 0, stream>>>(src, dst, gcnt, csrb);
    k_gemm1d <<<NBKT, TPB, 0, stream>>>(gcnt, csrb, x, W1, dinv, h1b);
    k_aggs1  <<<NBKT, TPB, 0, stream>>>(gcnt, csrb, h1b, dinv, b1, W2, g_s);
    k_aggs2  <<<NBKT, TPB, 0, stream>>>(gcnt, csrb, g_s, dinv, b2, out);
}